// Round 1
// baseline (37.922 us; speedup 1.0000x reference)
//
#include <hip/hip_runtime.h>

#define FK_NQ 7
#define FK_BLOCK 256

__global__ __launch_bounds__(FK_BLOCK) void fk_kernel(
    const float* __restrict__ q,
    const float* __restrict__ joint_xyz,
    const float* __restrict__ joint_rpy,
    const float* __restrict__ joint_axis,
    const float* __restrict__ link_xyz,
    const int*   __restrict__ idxp,
    float* __restrict__ out,
    int nb)
{
    // Batch-invariant per-joint constants (computed once per block, tiny)
    __shared__ float sB0[FK_NQ][9];   // R_joint
    __shared__ float sB1[FK_NQ][9];   // R_joint @ cross_matrix(w)
    __shared__ float su[FK_NQ][3];    // R_joint @ w
    __shared__ float sw[FK_NQ][3];    // w (joint axis, unnormalized)
    __shared__ float snn[FK_NQ];      // |w|
    __shared__ float sninv[FK_NQ];    // 1/|w|
    __shared__ float sninv2[FK_NQ];   // 1/|w|^2
    __shared__ float st[FK_NQ][3];    // joint_xyz
    __shared__ float sp[3];           // link_xyz[idx]
    __shared__ float sq[FK_BLOCK * FK_NQ];

    const int tid = threadIdx.x;

    if (tid < FK_NQ) {
        const int j = tid;
        float rr = joint_rpy[j*3+0], pp = joint_rpy[j*3+1], yy = joint_rpy[j*3+2];
        float sr, cr, spp, cpp, sy, cy;
        sincosf(rr, &sr, &cr);
        sincosf(pp, &spp, &cpp);
        sincosf(yy, &sy, &cy);
        // R_joint = Rz(yy) @ Ry(pp) @ Rx(rr)
        float R[3][3];
        R[0][0] = cy*cpp;  R[0][1] = cy*spp*sr - sy*cr;  R[0][2] = cy*spp*cr + sy*sr;
        R[1][0] = sy*cpp;  R[1][1] = sy*spp*sr + cy*cr;  R[1][2] = sy*spp*cr - cy*sr;
        R[2][0] = -spp;    R[2][1] = cpp*sr;             R[2][2] = cpp*cr;

        float w0 = joint_axis[j*3+0], w1 = joint_axis[j*3+1], w2 = joint_axis[j*3+2];
        float n2 = w0*w0 + w1*w1 + w2*w2;
        float n  = sqrtf(n2);
        #pragma unroll
        for (int r = 0; r < 3; ++r) {
            sB0[j][r*3+0] = R[r][0]; sB0[j][r*3+1] = R[r][1]; sB0[j][r*3+2] = R[r][2];
            // row r of R_joint @ W(w) == cross(R_row, w)
            sB1[j][r*3+0] = R[r][1]*w2 - R[r][2]*w1;
            sB1[j][r*3+1] = R[r][2]*w0 - R[r][0]*w2;
            sB1[j][r*3+2] = R[r][0]*w1 - R[r][1]*w0;
            su[j][r] = R[r][0]*w0 + R[r][1]*w1 + R[r][2]*w2;
        }
        sw[j][0] = w0; sw[j][1] = w1; sw[j][2] = w2;
        snn[j] = n; sninv[j] = 1.0f/n; sninv2[j] = 1.0f/n2;
        st[j][0] = joint_xyz[j*3+0]; st[j][1] = joint_xyz[j*3+1]; st[j][2] = joint_xyz[j*3+2];
    } else if (tid == FK_NQ) {
        int ix = idxp[0];
        sp[0] = link_xyz[ix*3+0]; sp[1] = link_xyz[ix*3+1]; sp[2] = link_xyz[ix*3+2];
    }

    // Stage this block's q slice coalesced into LDS
    const long bbase = (long)blockIdx.x * FK_BLOCK;
    const long qbase = bbase * FK_NQ;
    const long qtot  = (long)nb * FK_NQ;
    #pragma unroll
    for (int i = tid; i < FK_BLOCK * FK_NQ; i += FK_BLOCK) {
        long g = qbase + i;
        sq[i] = (g < qtot) ? q[g] : 0.0f;
    }
    __syncthreads();

    const long b = bbase + tid;
    if (b >= nb) return;

    float M[3][3], t[3];
    float A[3][3];

    #pragma unroll
    for (int j = 0; j < FK_NQ; ++j) {
        float th = sq[tid*FK_NQ + j];
        float sv, cv;
        sincosf(snn[j]*th, &sv, &cv);
        float a  = sv * sninv[j];
        float bb = (1.0f - cv) * sninv2[j];
        float bu[3] = { bb*su[j][0], bb*su[j][1], bb*su[j][2] };
        #pragma unroll
        for (int r = 0; r < 3; ++r) {
            #pragma unroll
            for (int c = 0; c < 3; ++c) {
                A[r][c] = cv*sB0[j][r*3+c] + a*sB1[j][r*3+c] + bu[r]*sw[j][c];
            }
        }
        if (j == 0) {
            #pragma unroll
            for (int r = 0; r < 3; ++r) {
                M[r][0] = A[r][0]; M[r][1] = A[r][1]; M[r][2] = A[r][2];
            }
            t[0] = st[0][0]; t[1] = st[0][1]; t[2] = st[0][2];
        } else {
            float t0 = st[j][0], t1 = st[j][1], t2 = st[j][2];
            #pragma unroll
            for (int r = 0; r < 3; ++r)
                t[r] += M[r][0]*t0 + M[r][1]*t1 + M[r][2]*t2;
            #pragma unroll
            for (int r = 0; r < 3; ++r) {
                float m0 = M[r][0], m1 = M[r][1], m2 = M[r][2];
                #pragma unroll
                for (int c = 0; c < 3; ++c)
                    M[r][c] = m0*A[0][c] + m1*A[1][c] + m2*A[2][c];
            }
        }
    }

    const float p0 = sp[0], p1 = sp[1], p2 = sp[2];
    float4* o = (float4*)(out + b*16);
    float4 row;
    row.x = M[0][0]; row.y = M[0][1]; row.z = M[0][2];
    row.w = M[0][0]*p0 + M[0][1]*p1 + M[0][2]*p2 + t[0];
    o[0] = row;
    row.x = M[1][0]; row.y = M[1][1]; row.z = M[1][2];
    row.w = M[1][0]*p0 + M[1][1]*p1 + M[1][2]*p2 + t[1];
    o[1] = row;
    row.x = M[2][0]; row.y = M[2][1]; row.z = M[2][2];
    row.w = M[2][0]*p0 + M[2][1]*p1 + M[2][2]*p2 + t[2];
    o[2] = row;
    row.x = 0.0f; row.y = 0.0f; row.z = 0.0f; row.w = 1.0f;
    o[3] = row;
}

extern "C" void kernel_launch(void* const* d_in, const int* in_sizes, int n_in,
                              void* d_out, int out_size, void* d_ws, size_t ws_size,
                              hipStream_t stream) {
    const float* q          = (const float*)d_in[0];
    const float* joint_xyz  = (const float*)d_in[1];
    const float* joint_rpy  = (const float*)d_in[2];
    const float* joint_axis = (const float*)d_in[3];
    const float* link_xyz   = (const float*)d_in[4];
    const int*   idxp       = (const int*)d_in[5];
    float* out = (float*)d_out;

    const int nb = in_sizes[0] / FK_NQ;
    const int grid = (nb + FK_BLOCK - 1) / FK_BLOCK;
    fk_kernel<<<grid, FK_BLOCK, 0, stream>>>(q, joint_xyz, joint_rpy, joint_axis,
                                             link_xyz, idxp, out, nb);
}

// Round 2
// 32.637 us; speedup vs baseline: 1.1619x; 1.1619x over previous
//
#include <hip/hip_runtime.h>

#define FK_NQ 7
#define FK_BLOCK 256

__global__ __launch_bounds__(FK_BLOCK) void fk_kernel(
    const float* __restrict__ q,
    const float* __restrict__ joint_xyz,
    const float* __restrict__ joint_rpy,
    const float* __restrict__ joint_axis,
    const float* __restrict__ link_xyz,
    const int*   __restrict__ idxp,
    float* __restrict__ out,
    int nb)
{
    // Batch-invariant per-joint constants (computed once per block, tiny)
    __shared__ float sB0[FK_NQ][9];   // R_joint
    __shared__ float sB1[FK_NQ][9];   // R_joint @ cross_matrix(w)
    __shared__ float su[FK_NQ][3];    // R_joint @ w
    __shared__ float sw[FK_NQ][3];    // w (joint axis, unnormalized)
    __shared__ float snn[FK_NQ];      // |w|
    __shared__ float sninv[FK_NQ];    // 1/|w|
    __shared__ float sninv2[FK_NQ];   // 1/|w|^2
    __shared__ float st[FK_NQ][3];    // joint_xyz
    __shared__ float sp[3];           // link_xyz[idx]
    __shared__ float sq[FK_BLOCK * FK_NQ];

    const int tid = threadIdx.x;

    if (tid < FK_NQ) {
        const int j = tid;
        float rr = joint_rpy[j*3+0], pp = joint_rpy[j*3+1], yy = joint_rpy[j*3+2];
        float sr, cr, spp, cpp, sy, cy;
        __sincosf(rr, &sr, &cr);
        __sincosf(pp, &spp, &cpp);
        __sincosf(yy, &sy, &cy);
        // R_joint = Rz(yy) @ Ry(pp) @ Rx(rr)
        float R[3][3];
        R[0][0] = cy*cpp;  R[0][1] = cy*spp*sr - sy*cr;  R[0][2] = cy*spp*cr + sy*sr;
        R[1][0] = sy*cpp;  R[1][1] = sy*spp*sr + cy*cr;  R[1][2] = sy*spp*cr - cy*sr;
        R[2][0] = -spp;    R[2][1] = cpp*sr;             R[2][2] = cpp*cr;

        float w0 = joint_axis[j*3+0], w1 = joint_axis[j*3+1], w2 = joint_axis[j*3+2];
        float n2 = w0*w0 + w1*w1 + w2*w2;
        float n  = sqrtf(n2);
        #pragma unroll
        for (int r = 0; r < 3; ++r) {
            sB0[j][r*3+0] = R[r][0]; sB0[j][r*3+1] = R[r][1]; sB0[j][r*3+2] = R[r][2];
            // row r of R_joint @ W(w) == cross(R_row, w)
            sB1[j][r*3+0] = R[r][1]*w2 - R[r][2]*w1;
            sB1[j][r*3+1] = R[r][2]*w0 - R[r][0]*w2;
            sB1[j][r*3+2] = R[r][0]*w1 - R[r][1]*w0;
            su[j][r] = R[r][0]*w0 + R[r][1]*w1 + R[r][2]*w2;
        }
        sw[j][0] = w0; sw[j][1] = w1; sw[j][2] = w2;
        snn[j] = n; sninv[j] = 1.0f/n; sninv2[j] = 1.0f/n2;
        st[j][0] = joint_xyz[j*3+0]; st[j][1] = joint_xyz[j*3+1]; st[j][2] = joint_xyz[j*3+2];
    } else if (tid == FK_NQ) {
        int ix = idxp[0];
        sp[0] = link_xyz[ix*3+0]; sp[1] = link_xyz[ix*3+1]; sp[2] = link_xyz[ix*3+2];
    }

    // Stage this block's q slice coalesced into LDS
    const long bbase = (long)blockIdx.x * FK_BLOCK;
    const long qbase = bbase * FK_NQ;
    const long qtot  = (long)nb * FK_NQ;
    #pragma unroll
    for (int i = tid; i < FK_BLOCK * FK_NQ; i += FK_BLOCK) {
        long g = qbase + i;
        sq[i] = (g < qtot) ? q[g] : 0.0f;
    }
    __syncthreads();

    const long b = bbase + tid;
    if (b >= nb) return;

    // Hoist all 7 sincos evaluations: independent, issue back-to-back (ILP),
    // only the compose chain below is serial.
    float sv[FK_NQ], cv[FK_NQ];
    #pragma unroll
    for (int j = 0; j < FK_NQ; ++j) {
        float x = snn[j] * sq[tid*FK_NQ + j];
        __sincosf(x, &sv[j], &cv[j]);
    }

    float M[3][3], t[3];
    float A[3][3];

    #pragma unroll
    for (int j = 0; j < FK_NQ; ++j) {
        float a  = sv[j] * sninv[j];
        float bb = (1.0f - cv[j]) * sninv2[j];
        float c  = cv[j];
        float bu[3] = { bb*su[j][0], bb*su[j][1], bb*su[j][2] };
        #pragma unroll
        for (int r = 0; r < 3; ++r) {
            #pragma unroll
            for (int cc = 0; cc < 3; ++cc) {
                A[r][cc] = c*sB0[j][r*3+cc] + a*sB1[j][r*3+cc] + bu[r]*sw[j][cc];
            }
        }
        if (j == 0) {
            #pragma unroll
            for (int r = 0; r < 3; ++r) {
                M[r][0] = A[r][0]; M[r][1] = A[r][1]; M[r][2] = A[r][2];
            }
            t[0] = st[0][0]; t[1] = st[0][1]; t[2] = st[0][2];
        } else {
            float t0 = st[j][0], t1 = st[j][1], t2 = st[j][2];
            #pragma unroll
            for (int r = 0; r < 3; ++r)
                t[r] += M[r][0]*t0 + M[r][1]*t1 + M[r][2]*t2;
            #pragma unroll
            for (int r = 0; r < 3; ++r) {
                float m0 = M[r][0], m1 = M[r][1], m2 = M[r][2];
                #pragma unroll
                for (int cc = 0; cc < 3; ++cc)
                    M[r][cc] = m0*A[0][cc] + m1*A[1][cc] + m2*A[2][cc];
            }
        }
    }

    const float p0 = sp[0], p1 = sp[1], p2 = sp[2];
    float4* o = (float4*)(out + b*16);
    float4 row;
    row.x = M[0][0]; row.y = M[0][1]; row.z = M[0][2];
    row.w = M[0][0]*p0 + M[0][1]*p1 + M[0][2]*p2 + t[0];
    o[0] = row;
    row.x = M[1][0]; row.y = M[1][1]; row.z = M[1][2];
    row.w = M[1][0]*p0 + M[1][1]*p1 + M[1][2]*p2 + t[1];
    o[1] = row;
    row.x = M[2][0]; row.y = M[2][1]; row.z = M[2][2];
    row.w = M[2][0]*p0 + M[2][1]*p1 + M[2][2]*p2 + t[2];
    o[2] = row;
    row.x = 0.0f; row.y = 0.0f; row.z = 0.0f; row.w = 1.0f;
    o[3] = row;
}

extern "C" void kernel_launch(void* const* d_in, const int* in_sizes, int n_in,
                              void* d_out, int out_size, void* d_ws, size_t ws_size,
                              hipStream_t stream) {
    const float* q          = (const float*)d_in[0];
    const float* joint_xyz  = (const float*)d_in[1];
    const float* joint_rpy  = (const float*)d_in[2];
    const float* joint_axis = (const float*)d_in[3];
    const float* link_xyz   = (const float*)d_in[4];
    const int*   idxp       = (const int*)d_in[5];
    float* out = (float*)d_out;

    const int nb = in_sizes[0] / FK_NQ;
    const int grid = (nb + FK_BLOCK - 1) / FK_BLOCK;
    fk_kernel<<<grid, FK_BLOCK, 0, stream>>>(q, joint_xyz, joint_rpy, joint_axis,
                                             link_xyz, idxp, out, nb);
}